// Round 11
// baseline (186.264 us; speedup 1.0000x reference)
//
#include <hip/hip_runtime.h>

typedef __bf16 bf16;
typedef bf16  bf16x8 __attribute__((ext_vector_type(8)));
typedef bf16  bf16x4 __attribute__((ext_vector_type(4)));
typedef float f32x4  __attribute__((ext_vector_type(4)));
typedef unsigned int u32x2 __attribute__((ext_vector_type(2)));
typedef unsigned int u32x4 __attribute__((ext_vector_type(4)));

#define MFMA16(a, b, c) __builtin_amdgcn_mfma_f32_16x16x32_bf16((a), (b), (c), 0, 0, 0)
#define AS1 __attribute__((address_space(1)))
#define AS3 __attribute__((address_space(3)))

// async global->LDS, 16B per lane; LDS dest = (wave-uniform) base + lane*16
__device__ __forceinline__ void gld_lds16(const bf16* g, bf16* l) {
    __builtin_amdgcn_global_load_lds((AS1 void*)(g), (AS3 void*)(l), 16, 0, 0);
}

// XOR swizzle (all LDS tiles): [rows][32] 64B rows; logical chunk c of row r at c^((r>>1)&3).
// Staging permutes the GLOBAL source: logical chunk = (lane&3) ^ ((lane>>3)&3).

// ---------------- fused fp32 -> bf16 casts (x + 4 weights, one dispatch) ----------------
__global__ __launch_bounds__(256) void cvt_all(const float* __restrict__ x,
                                               const float* __restrict__ Wq, const float* __restrict__ Wk,
                                               const float* __restrict__ Wv, const float* __restrict__ Wu,
                                               bf16* ox, bf16* oq, bf16* ok, bf16* ov, bf16* ou,
                                               float sq, float sk) {
    int bid = blockIdx.x;
    const float* src; bf16* dst; float sc; int base;
    if (bid < 4096) { src = x; dst = ox; sc = 1.0f; base = bid; }
    else {
        int w = (bid - 4096) >> 10; base = (bid - 4096) & 1023;
        switch (w) {
            case 0:  src = Wq; dst = oq; sc = sq;   break;
            case 1:  src = Wk; dst = ok; sc = sk;   break;
            case 2:  src = Wv; dst = ov; sc = 1.0f; break;
            default: src = Wu; dst = ou; sc = 1.0f; break;
        }
    }
    int idx = (base * 256 + threadIdx.x) * 4;
    float4 v = *(const float4*)(src + idx);
    bf16x4 o;
    o[0] = (bf16)(v.x * sc); o[1] = (bf16)(v.y * sc);
    o[2] = (bf16)(v.z * sc); o[3] = (bf16)(v.w * sc);
    *(bf16x4*)(dst + idx) = o;
}

// ---------------- 128x128 NT-GEMM core, 2-barrier (R1-verified BEST) — used by gemm_qkv ----------
// qkv runs 768 blocks at 3/CU: cross-block TLP already pipelines this structure. Three
// restructures (R3 dbuf, R4 256^2-2phase, R8 256^2 counted-vmcnt) all measured <= this.
__device__ __forceinline__ void gemm_core(const bf16* __restrict__ A, const bf16* __restrict__ B,
                                          int mBase, int nBase, bf16* As, bf16* Bs,
                                          f32x4 acc[4][4]) {
    const int tid = threadIdx.x;
    const int wave = tid >> 6, lane = tid & 63;
    const int g = lane >> 4, lr = lane & 15;
    const int wm = (wave & 1) << 6, wn = (wave >> 1) << 6;
    const int q = lane >> 2;
    const int cswz = ((lane & 3) ^ ((lane >> 3) & 3)) << 3;
    const int pcs  = (g ^ ((lr >> 1) & 3)) << 3;

    const int rb0 = wave << 4, rb1 = rb0 + 64;
    const bf16* a0 = A + (size_t)(mBase + rb0 + q) * 1024 + cswz;
    const bf16* a1 = A + (size_t)(mBase + rb1 + q) * 1024 + cswz;
    const bf16* b0 = B + (size_t)(nBase + rb0 + q) * 1024 + cswz;
    const bf16* b1 = B + (size_t)(nBase + rb1 + q) * 1024 + cswz;

    for (int k0 = 0; k0 < 1024; k0 += 32) {
        __syncthreads();
        gld_lds16(a0 + k0, As + rb0 * 32);
        gld_lds16(a1 + k0, As + rb1 * 32);
        gld_lds16(b0 + k0, Bs + rb0 * 32);
        gld_lds16(b1 + k0, Bs + rb1 * 32);
        __syncthreads();

        bf16x8 af[4], bfr[4];
#pragma unroll
        for (int i = 0; i < 4; i++)
            af[i] = *(const bf16x8*)&As[(wm + (i << 4) + lr) * 32 + pcs];
#pragma unroll
        for (int j = 0; j < 4; j++)
            bfr[j] = *(const bf16x8*)&Bs[(wn + (j << 4) + lr) * 32 + pcs];
#pragma unroll
        for (int i = 0; i < 4; i++)
#pragma unroll
            for (int j = 0; j < 4; j++)
                acc[i][j] = MFMA16(af[i], bfr[j], acc[i][j]);
    }
}

// ---------------- 128x128 NT-GEMM core, DBUF single-barrier (R9-verified WIN) — gemm_out only ------
// gemm_out is grid-starved (1 block/CU, no TLP): dbuf hides the staging drain there.
// R9 de-confound: dbuf on gemm_out only = 181.7 -> 178.2us.
__device__ __forceinline__ void gemm_core_dbuf(const bf16* __restrict__ A, const bf16* __restrict__ B,
                                               int mBase, int nBase, bf16* As, bf16* Bs,
                                               f32x4 acc[4][4]) {
    const int tid = threadIdx.x;
    const int wave = tid >> 6, lane = tid & 63;
    const int g = lane >> 4, lr = lane & 15;
    const int wm = (wave & 1) << 6, wn = (wave >> 1) << 6;
    const int q = lane >> 2;
    const int cswz = ((lane & 3) ^ ((lane >> 3) & 3)) << 3;
    const int pcs  = (g ^ ((lr >> 1) & 3)) << 3;

    const int rb0 = wave << 4, rb1 = rb0 + 64;
    const bf16* a0 = A + (size_t)(mBase + rb0 + q) * 1024 + cswz;
    const bf16* a1 = A + (size_t)(mBase + rb1 + q) * 1024 + cswz;
    const bf16* b0 = B + (size_t)(nBase + rb0 + q) * 1024 + cswz;
    const bf16* b1 = B + (size_t)(nBase + rb1 + q) * 1024 + cswz;

    gld_lds16(a0, As + rb0 * 32);
    gld_lds16(a1, As + rb1 * 32);
    gld_lds16(b0, Bs + rb0 * 32);
    gld_lds16(b1, Bs + rb1 * 32);
    __syncthreads();

    for (int k0 = 0; k0 < 1024; k0 += 32) {
        const int cur = (k0 >> 5) & 1;
        bf16* Asc = As + cur * (128 * 32);
        bf16* Bsc = Bs + cur * (128 * 32);
        if (k0 + 32 < 1024) {
            bf16* Asn = As + (cur ^ 1) * (128 * 32);
            bf16* Bsn = Bs + (cur ^ 1) * (128 * 32);
            gld_lds16(a0 + k0 + 32, Asn + rb0 * 32);
            gld_lds16(a1 + k0 + 32, Asn + rb1 * 32);
            gld_lds16(b0 + k0 + 32, Bsn + rb0 * 32);
            gld_lds16(b1 + k0 + 32, Bsn + rb1 * 32);
        }

        bf16x8 af[4], bfr[4];
#pragma unroll
        for (int i = 0; i < 4; i++)
            af[i] = *(const bf16x8*)&Asc[(wm + (i << 4) + lr) * 32 + pcs];
#pragma unroll
        for (int j = 0; j < 4; j++)
            bfr[j] = *(const bf16x8*)&Bsc[(wn + (j << 4) + lr) * 32 + pcs];
#pragma unroll
        for (int i = 0; i < 4; i++)
#pragma unroll
            for (int j = 0; j < 4; j++)
                acc[i][j] = MFMA16(af[i], bfr[j], acc[i][j]);

        __syncthreads();
    }
}

// ---------------- merged QKV GEMM (R1-verified BEST config) ----------------
__global__ __launch_bounds__(256) void gemm_qkv(const bf16* __restrict__ X,
                                                const bf16* __restrict__ Wqk,  // [2048][1024]
                                                const bf16* __restrict__ Wv,
                                                bf16* __restrict__ Qo, bf16* __restrict__ Ko,
                                                bf16* __restrict__ Vto) {
    __shared__ bf16 As[128 * 32];
    __shared__ bf16 Bs[128 * 32];
    const int tid = threadIdx.x;
    const int wave = tid >> 6, lane = tid & 63;
    const int g = lane >> 4, lr = lane & 15;
    const int wm = (wave & 1) << 6, wn = (wave >> 1) << 6;
    const int my = blockIdx.y;
    const bool qk = (my < 16);

    const bf16* Ap = qk ? Wqk : X;
    const bf16* Bp = qk ? X   : Wv;
    const int mBase = qk ? my * 128 : blockIdx.x * 128;
    const int nBase = qk ? blockIdx.x * 128 : (my - 16) * 128;

    f32x4 acc[4][4] = {};
    gemm_core(Ap, Bp, mBase, nBase, As, Bs, acc);

    if (qk) {
#pragma unroll
        for (int i = 0; i < 4; i++) {
            int m0 = mBase + wm + (i << 4) + (g << 2);
            bf16* dst = (m0 >> 10) ? Ko : Qo;
            int feat = m0 & 1023;
            int h = feat >> 6, d = feat & 63;
#pragma unroll
            for (int j = 0; j < 4; j++) {
                int t = nBase + wn + (j << 4) + lr;
                int b = t >> 11, tl = t & 2047;
                bf16x4 v;
#pragma unroll
                for (int r = 0; r < 4; r++) v[r] = (bf16)acc[i][j][r];
                *(bf16x4*)&dst[(((size_t)((b << 4) + h) * 2048 + tl) << 6) + d] = v;
            }
        }
    } else {
#pragma unroll
        for (int i = 0; i < 4; i++) {
            int t0 = mBase + wm + (i << 4) + (g << 2);
            int b = t0 >> 11, tl = t0 & 2047;
#pragma unroll
            for (int j = 0; j < 4; j++) {
                int o = nBase + wn + (j << 4) + lr;
                int h = o >> 6, d = o & 63;
                bf16x4 v;
#pragma unroll
                for (int r = 0; r < 4; r++) v[r] = (bf16)acc[i][j][r];
                *(bf16x4*)&Vto[((size_t)(((b << 4) + h) << 6) + d) * 2048 + tl] = v;
            }
        }
    }
}

// ---------------- output GEMM (role-swapped, DBUF core): out = attn @ Wu^T + bu ----------------
__global__ __launch_bounds__(256) void gemm_out(const bf16* __restrict__ Wu, const bf16* __restrict__ A,
                                                const float* __restrict__ bias, float* __restrict__ out) {
    __shared__ bf16 As[2][128 * 32];
    __shared__ bf16 Bs[2][128 * 32];
    const int tid = threadIdx.x;
    const int wave = tid >> 6, lane = tid & 63;
    const int g = lane >> 4, lr = lane & 15;
    const int wm = (wave & 1) << 6, wn = (wave >> 1) << 6;
    const int mBase = blockIdx.y * 128, nBase = blockIdx.x * 128;

    f32x4 acc[4][4] = {};
    gemm_core_dbuf(Wu, A, mBase, nBase, &As[0][0], &Bs[0][0], acc);

#pragma unroll
    for (int i = 0; i < 4; i++) {
        int o = mBase + wm + (i << 4) + (g << 2);
        float4 bv = *(const float4*)&bias[o];
#pragma unroll
        for (int j = 0; j < 4; j++) {
            int t = nBase + wn + (j << 4) + lr;
            float4 v;
            v.x = acc[i][j][0] + bv.x;
            v.y = acc[i][j][1] + bv.y;
            v.z = acc[i][j][2] + bv.z;
            v.w = acc[i][j][3] + bv.w;
            *(float4*)&out[((size_t)t << 10) + o] = v;
        }
    }
}

// ---------------- attention v8: v6 + T14 reg-staged async K/V (issue-early, write-late) ----------
// v6's staging was: barrier -> issue 32KB DMA -> barrier(vmcnt0 DRAIN) -> compute. The full
// L2 delivery (~2300cy/CU-iter) sat exposed between barriers, 16x/block — same disease
// R9 cured on gemm_out. v8: per-thread u32x4 loads from the IDENTICAL swizzled global
// addresses into 8 staging reg-quads, ds_write_b128 to the IDENTICAL linear LDS bytes
// (lane*16 within each 1KB chunk — byte-for-byte the DMA placement; fragment reads
// untouched). Loop: lgkm0+barrier -> ds_write -> lgkm0 -> issue next loads -> barrier ->
// compute. NO vmcnt at barriers: next chunk's loads fly across the whole compute phase.
// WAR on staging regs cleared by the lgkm0 between writes and loads (rule #18: sched
// _barrier(0) pins each inline-asm wait). VGPR 60 -> ~95; LDS unchanged 40KB, 4 blk/CU.
__global__ __launch_bounds__(256, 4) void attn(const bf16* __restrict__ Q, const bf16* __restrict__ Kt,
                                               const bf16* __restrict__ Vt, bf16* __restrict__ O) {
    __shared__ bf16 Qs[2][64][32];    // 8KB [ks][t][d-half]; dead after qf
    __shared__ bf16 Ks[2][128][32];   // 16KB [ks][s][d-half]
    __shared__ bf16 Vs[4][64][32];    // 16KB [s32-block][d][s-quarter]

    const int tid = threadIdx.x;
    const int wave = tid >> 6, lane = tid & 63;
    const int g = lane >> 4, lr = lane & 15;
    const int q = lane >> 2;
    const int cswz = ((lane & 3) ^ ((lane >> 3) & 3)) << 3;
    const int pcs  = (g ^ ((lr >> 1) & 3)) << 3;
    const int pair = wave >> 1;       // t-half (32 t)
    const int shalf = wave & 1;       // s-half (64 s per 128-chunk)

    const int bid = blockIdx.x;
    const int bh = ((bid & 7) << 2) | (bid >> 8);   // XCD-affinity
    const int qBase = ((bid >> 3) & 31) << 6;

    const bf16* Qg = Q + ((size_t)bh * 2048 + qBase) * 64;
    const bf16* Kg = Kt + (size_t)bh * 2048 * 64;
    const bf16* Vg = Vt + (size_t)bh * 64 * 2048;

    // stage Q: 8 batches of 1KB, 2 per wave, plane-split, swizzled source (DMA fine here:
    // one-shot prologue, latency amortized over the whole kernel)
#pragma unroll
    for (int i = 0; i < 2; i++) {
        int bi = (wave << 1) + i;
        int p = bi >> 2, rb = (bi & 3) << 4;
        gld_lds16(Qg + (rb + q) * 64 + (p << 5) + cswz, &Qs[p][rb][0]);
    }

    // T14 prologue: issue chunk-0 K/V loads to registers (fly under Q staging + qf reads)
    u32x4 kreg[4], vreg[4];
#pragma unroll
    for (int i = 0; i < 4; i++) {
        int bi = (wave << 2) + i;
        { int p = bi >> 3, rb = (bi & 7) << 4;
          kreg[i] = *(const u32x4*)(Kg + (size_t)(rb + q) * 64 + (p << 5) + cswz); }
        { int p = bi >> 2, rb = (bi & 3) << 4;
          vreg[i] = *(const u32x4*)(Vg + (size_t)(rb + q) * 2048 + (p << 5) + cswz); }
    }

    __syncthreads();   // Q resident

    bf16x8 qf[2][2];   // [ks][tt] — this wave's 2 t-tiles
#pragma unroll
    for (int ks = 0; ks < 2; ks++)
#pragma unroll
        for (int tt = 0; tt < 2; tt++)
            qf[ks][tt] = *(const bf16x8*)&Qs[ks][(pair << 5) + (tt << 4) + lr][pcs];

    bf16x8 ones;
#pragma unroll
    for (int i = 0; i < 8; i++) ones[i] = (bf16)1.0f;

    f32x4 oacc[2][4] = {};   // [tt][jd]
    f32x4 oaccL[2] = {};

    for (int s0 = 0; s0 < 2048; s0 += 128) {
        // barrier A: all waves' prior-chunk LDS reads done (lgkm only — prefetch keeps flying)
        asm volatile("s_waitcnt lgkmcnt(0)" ::: "memory");
        __builtin_amdgcn_s_barrier();
        __builtin_amdgcn_sched_barrier(0);

        // write staged chunk regs -> LDS (compiler inserts the vmcnt wait for these regs —
        // their loads flew across the previous compute phase)
#pragma unroll
        for (int i = 0; i < 4; i++) {
            int bi = (wave << 2) + i;
            { int p = bi >> 3, rb = (bi & 7) << 4;
              *(u32x4*)((char*)&Ks[p][rb][0] + (lane << 4)) = kreg[i]; }
            { int p = bi >> 2, rb = (bi & 3) << 4;
              *(u32x4*)((char*)&Vs[p][rb][0] + (lane << 4)) = vreg[i]; }
        }
        asm volatile("s_waitcnt lgkmcnt(0)" ::: "memory");   // my writes done; clears reg WAR
        __builtin_amdgcn_sched_barrier(0);

        // issue next-chunk loads (land during compute below)
        if (s0 + 128 < 2048) {
            const int sn = s0 + 128;
#pragma unroll
            for (int i = 0; i < 4; i++) {
                int bi = (wave << 2) + i;
                { int p = bi >> 3, rb = (bi & 7) << 4;
                  kreg[i] = *(const u32x4*)(Kg + (size_t)(sn + rb + q) * 64 + (p << 5) + cswz); }
                { int p = bi >> 2, rb = (bi & 3) << 4;
                  vreg[i] = *(const u32x4*)(Vg + (size_t)(rb + q) * 2048 + sn + (p << 5) + cswz); }
            }
        }
        __builtin_amdgcn_sched_barrier(0);
        __builtin_amdgcn_s_barrier();   // barrier B: every wave's ds_writes complete -> chunk visible

#pragma unroll
        for (int sblk = 0; sblk < 2; sblk++) {
            // S^T for this wave's 32-s sub-slice x its 32 t
            f32x4 sacc[2][2] = {};   // [isub][tt]
#pragma unroll
            for (int ks = 0; ks < 2; ks++)
#pragma unroll
                for (int isub = 0; isub < 2; isub++) {
                    bf16x8 kf = *(const bf16x8*)
                        &Ks[ks][(shalf << 6) + (sblk << 5) + (isub << 4) + lr][pcs];
                    sacc[isub][0] = MFMA16(kf, qf[ks][0], sacc[isub][0]);
                    sacc[isub][1] = MFMA16(kf, qf[ks][1], sacc[isub][1]);
                }
            // exp2 + in-register redistribution into PV A-fragments (no LDS)
            bf16x8 pf[2];
#pragma unroll
            for (int tt = 0; tt < 2; tt++) {
                bf16x4 e0, e1;
#pragma unroll
                for (int r = 0; r < 4; r++) {
                    e0[r] = (bf16)__builtin_amdgcn_exp2f(sacc[0][tt][r]);   // s = 4g+r
                    e1[r] = (bf16)__builtin_amdgcn_exp2f(sacc[1][tt][r]);   // s = 16+4g+r
                }
                u32x2 a = __builtin_bit_cast(u32x2, e0);
                u32x2 b = __builtin_bit_cast(u32x2, e1);
                u32x2 t0  = __builtin_amdgcn_permlane32_swap(a.x, b.x, false, false);
                u32x2 w02 = __builtin_amdgcn_permlane16_swap(t0.x, t0.y, false, false);
                u32x2 t1  = __builtin_amdgcn_permlane32_swap(a.y, b.y, false, false);
                u32x2 w13 = __builtin_amdgcn_permlane16_swap(t1.x, t1.y, false, false);
                u32x4 w = {w02.x, w13.x, w02.y, w13.y};
                pf[tt] = __builtin_bit_cast(bf16x8, w);   // P[t=lr][s=8g+j]
            }
            // O += P @ V; L += P @ ones
#pragma unroll
            for (int jd = 0; jd < 4; jd++) {
                bf16x8 vf = *(const bf16x8*)&Vs[(shalf << 1) + sblk][(jd << 4) + lr][pcs];
                oacc[0][jd] = MFMA16(pf[0], vf, oacc[0][jd]);
                oacc[1][jd] = MFMA16(pf[1], vf, oacc[1][jd]);
            }
            oaccL[0] = MFMA16(pf[0], ones, oaccL[0]);
            oaccL[1] = MFMA16(pf[1], ones, oaccL[1]);
        }
    }

    // ---- endgame: 2-way cross-wave reduce (s-half partners share a t-pair) ----
    __syncthreads();   // all waves done with Ks/Vs
    float* Odump = (float*)&Ks[0][0][0];   // 16KB = 2 pairs x 2048 floats
    float* Ldump = (float*)&Vs[0][0][0];   // 4KB used
    if (shalf == 1) {
#pragma unroll
        for (int tt = 0; tt < 2; tt++) {
#pragma unroll
            for (int jd = 0; jd < 4; jd++)
                *(f32x4*)&Odump[(pair << 11) + (((tt << 2) + jd) << 8) + (lane << 2)] = oacc[tt][jd];
            *(f32x4*)&Ldump[(pair << 9) + (tt << 8) + (lane << 2)] = oaccL[tt];
        }
    }
    __syncthreads();
    if (shalf == 0) {
        const int b = bh >> 4, h = bh & 15;
#pragma unroll
        for (int tt = 0; tt < 2; tt++) {
            f32x4 Lp = *(const f32x4*)&Ldump[(pair << 9) + (tt << 8) + (lane << 2)];
            f32x4 Ls = oaccL[tt] + Lp;
            float linv[4];
#pragma unroll
            for (int r = 0; r < 4; r++) linv[r] = 1.0f / Ls[r];
#pragma unroll
            for (int jd = 0; jd < 4; jd++) {
                f32x4 Op = *(const f32x4*)&Odump[(pair << 11) + (((tt << 2) + jd) << 8) + (lane << 2)];
                f32x4 v = oacc[tt][jd] + Op;
#pragma unroll
                for (int r = 0; r < 4; r++) {
                    int t = qBase + (pair << 5) + (tt << 4) + (g << 2) + r;
                    int col = (h << 6) + (jd << 4) + lr;
                    O[(((size_t)(b * 2048 + t)) << 10) + col] = (bf16)(v[r] * linv[r]);
                }
            }
        }
    }
}

extern "C" void kernel_launch(void* const* d_in, const int* in_sizes, int n_in,
                              void* d_out, int out_size, void* d_ws, size_t ws_size,
                              hipStream_t stream) {
    const float* x  = (const float*)d_in[0];
    const float* Wq = (const float*)d_in[1];
    const float* Wk = (const float*)d_in[2];
    const float* Wv = (const float*)d_in[3];
    const float* Wu = (const float*)d_in[4];
    const float* bu = (const float*)d_in[5];
    float* out = (float*)d_out;

    char* ws = (char*)d_ws;
    bf16* xbf  = (bf16*)(ws);                      // 8MB; reused as attn output after QKV GEMM
    bf16* wqbf = (bf16*)(ws + ((size_t)8  << 20)); // wq+wk contiguous = stacked [2048][1024]
    bf16* wkbf = (bf16*)(ws + ((size_t)10 << 20));
    bf16* wvbf = (bf16*)(ws + ((size_t)12 << 20));
    bf16* wubf = (bf16*)(ws + ((size_t)14 << 20));
    bf16* Qb   = (bf16*)(ws + ((size_t)16 << 20)); // [b,h,t,d] 8MB
    bf16* Kb   = (bf16*)(ws + ((size_t)24 << 20)); // [b,h,t,d] 8MB
    bf16* Vtb  = (bf16*)(ws + ((size_t)32 << 20)); // [b,h,d,t] 8MB
    bf16* attnO = xbf;                             // overlay: x dead after gemm_qkv

    const float iscale_k = 0.17677669529663687f;   // 1024^-0.25
    const float iscale_q = 0.25503540109f;         // 1024^-0.25 * log2(e) -> scores in log2 domain

    cvt_all<<<8192, 256, 0, stream>>>(x, Wq, Wk, Wv, Wu, xbf, wqbf, wkbf, wvbf, wubf,
                                      iscale_q, iscale_k);

    gemm_qkv<<<dim3(32, 24), 256, 0, stream>>>(xbf, wqbf, wvbf, Qb, Kb, Vtb);
    attn<<<dim3(1024), 256, 0, stream>>>(Qb, Kb, Vtb, attnO);
    gemm_out<<<dim3(32, 8), 256, 0, stream>>>(wubf, attnO, bu, out);
}

// Round 12
// 179.005 us; speedup vs baseline: 1.0405x; 1.0405x over previous
//
#include <hip/hip_runtime.h>

typedef __bf16 bf16;
typedef bf16  bf16x8 __attribute__((ext_vector_type(8)));
typedef bf16  bf16x4 __attribute__((ext_vector_type(4)));
typedef float f32x4  __attribute__((ext_vector_type(4)));
typedef unsigned int u32x2 __attribute__((ext_vector_type(2)));
typedef unsigned int u32x4 __attribute__((ext_vector_type(4)));

#define MFMA16(a, b, c) __builtin_amdgcn_mfma_f32_16x16x32_bf16((a), (b), (c), 0, 0, 0)
#define AS1 __attribute__((address_space(1)))
#define AS3 __attribute__((address_space(3)))

// async global->LDS, 16B per lane; LDS dest = (wave-uniform) base + lane*16
__device__ __forceinline__ void gld_lds16(const bf16* g, bf16* l) {
    __builtin_amdgcn_global_load_lds((AS1 void*)(g), (AS3 void*)(l), 16, 0, 0);
}

// XOR swizzle (all LDS tiles): [rows][32] 64B rows; logical chunk c of row r at c^((r>>1)&3).
// Staging permutes the GLOBAL source: logical chunk = (lane&3) ^ ((lane>>3)&3).

// ---------------- fused fp32 -> bf16 casts (x + 4 weights, one dispatch) ----------------
__global__ __launch_bounds__(256) void cvt_all(const float* __restrict__ x,
                                               const float* __restrict__ Wq, const float* __restrict__ Wk,
                                               const float* __restrict__ Wv, const float* __restrict__ Wu,
                                               bf16* ox, bf16* oq, bf16* ok, bf16* ov, bf16* ou,
                                               float sq, float sk) {
    int bid = blockIdx.x;
    const float* src; bf16* dst; float sc; int base;
    if (bid < 4096) { src = x; dst = ox; sc = 1.0f; base = bid; }
    else {
        int w = (bid - 4096) >> 10; base = (bid - 4096) & 1023;
        switch (w) {
            case 0:  src = Wq; dst = oq; sc = sq;   break;
            case 1:  src = Wk; dst = ok; sc = sk;   break;
            case 2:  src = Wv; dst = ov; sc = 1.0f; break;
            default: src = Wu; dst = ou; sc = 1.0f; break;
        }
    }
    int idx = (base * 256 + threadIdx.x) * 4;
    float4 v = *(const float4*)(src + idx);
    bf16x4 o;
    o[0] = (bf16)(v.x * sc); o[1] = (bf16)(v.y * sc);
    o[2] = (bf16)(v.z * sc); o[3] = (bf16)(v.w * sc);
    *(bf16x4*)(dst + idx) = o;
}

// ---------------- 128x128 NT-GEMM core, 2-barrier (R1-verified BEST) — used by gemm_qkv ----------
// qkv runs 768 blocks at 3/CU: cross-block TLP already pipelines this structure. Three
// restructures (R3 dbuf, R4 256^2-2phase, R8 256^2 counted-vmcnt) all measured <= this.
__device__ __forceinline__ void gemm_core(const bf16* __restrict__ A, const bf16* __restrict__ B,
                                          int mBase, int nBase, bf16* As, bf16* Bs,
                                          f32x4 acc[4][4]) {
    const int tid = threadIdx.x;
    const int wave = tid >> 6, lane = tid & 63;
    const int g = lane >> 4, lr = lane & 15;
    const int wm = (wave & 1) << 6, wn = (wave >> 1) << 6;
    const int q = lane >> 2;
    const int cswz = ((lane & 3) ^ ((lane >> 3) & 3)) << 3;
    const int pcs  = (g ^ ((lr >> 1) & 3)) << 3;

    const int rb0 = wave << 4, rb1 = rb0 + 64;
    const bf16* a0 = A + (size_t)(mBase + rb0 + q) * 1024 + cswz;
    const bf16* a1 = A + (size_t)(mBase + rb1 + q) * 1024 + cswz;
    const bf16* b0 = B + (size_t)(nBase + rb0 + q) * 1024 + cswz;
    const bf16* b1 = B + (size_t)(nBase + rb1 + q) * 1024 + cswz;

    for (int k0 = 0; k0 < 1024; k0 += 32) {
        __syncthreads();
        gld_lds16(a0 + k0, As + rb0 * 32);
        gld_lds16(a1 + k0, As + rb1 * 32);
        gld_lds16(b0 + k0, Bs + rb0 * 32);
        gld_lds16(b1 + k0, Bs + rb1 * 32);
        __syncthreads();

        bf16x8 af[4], bfr[4];
#pragma unroll
        for (int i = 0; i < 4; i++)
            af[i] = *(const bf16x8*)&As[(wm + (i << 4) + lr) * 32 + pcs];
#pragma unroll
        for (int j = 0; j < 4; j++)
            bfr[j] = *(const bf16x8*)&Bs[(wn + (j << 4) + lr) * 32 + pcs];
#pragma unroll
        for (int i = 0; i < 4; i++)
#pragma unroll
            for (int j = 0; j < 4; j++)
                acc[i][j] = MFMA16(af[i], bfr[j], acc[i][j]);
    }
}

// ---------------- 128x128 NT-GEMM core, DBUF single-barrier (R9-verified WIN) — gemm_out only ------
// gemm_out is grid-starved (1 block/CU, no TLP): dbuf hides the staging drain there.
// R9 de-confound: dbuf on gemm_out only = 181.7 -> 178.2us.
__device__ __forceinline__ void gemm_core_dbuf(const bf16* __restrict__ A, const bf16* __restrict__ B,
                                               int mBase, int nBase, bf16* As, bf16* Bs,
                                               f32x4 acc[4][4]) {
    const int tid = threadIdx.x;
    const int wave = tid >> 6, lane = tid & 63;
    const int g = lane >> 4, lr = lane & 15;
    const int wm = (wave & 1) << 6, wn = (wave >> 1) << 6;
    const int q = lane >> 2;
    const int cswz = ((lane & 3) ^ ((lane >> 3) & 3)) << 3;
    const int pcs  = (g ^ ((lr >> 1) & 3)) << 3;

    const int rb0 = wave << 4, rb1 = rb0 + 64;
    const bf16* a0 = A + (size_t)(mBase + rb0 + q) * 1024 + cswz;
    const bf16* a1 = A + (size_t)(mBase + rb1 + q) * 1024 + cswz;
    const bf16* b0 = B + (size_t)(nBase + rb0 + q) * 1024 + cswz;
    const bf16* b1 = B + (size_t)(nBase + rb1 + q) * 1024 + cswz;

    gld_lds16(a0, As + rb0 * 32);
    gld_lds16(a1, As + rb1 * 32);
    gld_lds16(b0, Bs + rb0 * 32);
    gld_lds16(b1, Bs + rb1 * 32);
    __syncthreads();

    for (int k0 = 0; k0 < 1024; k0 += 32) {
        const int cur = (k0 >> 5) & 1;
        bf16* Asc = As + cur * (128 * 32);
        bf16* Bsc = Bs + cur * (128 * 32);
        if (k0 + 32 < 1024) {
            bf16* Asn = As + (cur ^ 1) * (128 * 32);
            bf16* Bsn = Bs + (cur ^ 1) * (128 * 32);
            gld_lds16(a0 + k0 + 32, Asn + rb0 * 32);
            gld_lds16(a1 + k0 + 32, Asn + rb1 * 32);
            gld_lds16(b0 + k0 + 32, Bsn + rb0 * 32);
            gld_lds16(b1 + k0 + 32, Bsn + rb1 * 32);
        }

        bf16x8 af[4], bfr[4];
#pragma unroll
        for (int i = 0; i < 4; i++)
            af[i] = *(const bf16x8*)&Asc[(wm + (i << 4) + lr) * 32 + pcs];
#pragma unroll
        for (int j = 0; j < 4; j++)
            bfr[j] = *(const bf16x8*)&Bsc[(wn + (j << 4) + lr) * 32 + pcs];
#pragma unroll
        for (int i = 0; i < 4; i++)
#pragma unroll
            for (int j = 0; j < 4; j++)
                acc[i][j] = MFMA16(af[i], bfr[j], acc[i][j]);

        __syncthreads();
    }
}

// ---------------- merged QKV GEMM (R1-verified BEST config) ----------------
__global__ __launch_bounds__(256) void gemm_qkv(const bf16* __restrict__ X,
                                                const bf16* __restrict__ Wqk,  // [2048][1024]
                                                const bf16* __restrict__ Wv,
                                                bf16* __restrict__ Qo, bf16* __restrict__ Ko,
                                                bf16* __restrict__ Vto) {
    __shared__ bf16 As[128 * 32];
    __shared__ bf16 Bs[128 * 32];
    const int tid = threadIdx.x;
    const int wave = tid >> 6, lane = tid & 63;
    const int g = lane >> 4, lr = lane & 15;
    const int wm = (wave & 1) << 6, wn = (wave >> 1) << 6;
    const int my = blockIdx.y;
    const bool qk = (my < 16);

    const bf16* Ap = qk ? Wqk : X;
    const bf16* Bp = qk ? X   : Wv;
    const int mBase = qk ? my * 128 : blockIdx.x * 128;
    const int nBase = qk ? blockIdx.x * 128 : (my - 16) * 128;

    f32x4 acc[4][4] = {};
    gemm_core(Ap, Bp, mBase, nBase, As, Bs, acc);

    if (qk) {
#pragma unroll
        for (int i = 0; i < 4; i++) {
            int m0 = mBase + wm + (i << 4) + (g << 2);
            bf16* dst = (m0 >> 10) ? Ko : Qo;
            int feat = m0 & 1023;
            int h = feat >> 6, d = feat & 63;
#pragma unroll
            for (int j = 0; j < 4; j++) {
                int t = nBase + wn + (j << 4) + lr;
                int b = t >> 11, tl = t & 2047;
                bf16x4 v;
#pragma unroll
                for (int r = 0; r < 4; r++) v[r] = (bf16)acc[i][j][r];
                *(bf16x4*)&dst[(((size_t)((b << 4) + h) * 2048 + tl) << 6) + d] = v;
            }
        }
    } else {
#pragma unroll
        for (int i = 0; i < 4; i++) {
            int t0 = mBase + wm + (i << 4) + (g << 2);
            int b = t0 >> 11, tl = t0 & 2047;
#pragma unroll
            for (int j = 0; j < 4; j++) {
                int o = nBase + wn + (j << 4) + lr;
                int h = o >> 6, d = o & 63;
                bf16x4 v;
#pragma unroll
                for (int r = 0; r < 4; r++) v[r] = (bf16)acc[i][j][r];
                *(bf16x4*)&Vto[((size_t)(((b << 4) + h) << 6) + d) * 2048 + tl] = v;
            }
        }
    }
}

// ---------------- output GEMM (role-swapped, DBUF core): out = attn @ Wu^T + bu ----------------
__global__ __launch_bounds__(256) void gemm_out(const bf16* __restrict__ Wu, const bf16* __restrict__ A,
                                                const float* __restrict__ bias, float* __restrict__ out) {
    __shared__ bf16 As[2][128 * 32];
    __shared__ bf16 Bs[2][128 * 32];
    const int tid = threadIdx.x;
    const int wave = tid >> 6, lane = tid & 63;
    const int g = lane >> 4, lr = lane & 15;
    const int wm = (wave & 1) << 6, wn = (wave >> 1) << 6;
    const int mBase = blockIdx.y * 128, nBase = blockIdx.x * 128;

    f32x4 acc[4][4] = {};
    gemm_core_dbuf(Wu, A, mBase, nBase, &As[0][0], &Bs[0][0], acc);

#pragma unroll
    for (int i = 0; i < 4; i++) {
        int o = mBase + wm + (i << 4) + (g << 2);
        float4 bv = *(const float4*)&bias[o];
#pragma unroll
        for (int j = 0; j < 4; j++) {
            int t = nBase + wn + (j << 4) + lr;
            float4 v;
            v.x = acc[i][j][0] + bv.x;
            v.y = acc[i][j][1] + bv.y;
            v.z = acc[i][j][2] + bv.z;
            v.w = acc[i][j][3] + bv.w;
            *(float4*)&out[((size_t)t << 10) + o] = v;
        }
    }
}

// ---------------- attention v9: v6 (R7/R8-best, 47.2us) + T5 setprio on MFMA clusters ----------
// v8 (T14 reg-staging) FALSIFIED in R11: 53.8us, WRITE_SIZE +2MB scratch spill — where
// global_load_lds works, DMA wins (m151); 4-blk/CU TLP already hides most of the drain.
// v9 = v6 byte-identical + __builtin_amdgcn_s_setprio(1)/(0) around the QK and PV MFMA
// clusters (T5: +4-7% on attn with multi-block phase diversity, m191; pure hint, no
// memory semantics — zero structural risk).
__global__ __launch_bounds__(256, 4) void attn(const bf16* __restrict__ Q, const bf16* __restrict__ Kt,
                                               const bf16* __restrict__ Vt, bf16* __restrict__ O) {
    __shared__ bf16 Qs[2][64][32];    // 8KB [ks][t][d-half]; dead after qf
    __shared__ bf16 Ks[2][128][32];   // 16KB [ks][s][d-half]
    __shared__ bf16 Vs[4][64][32];    // 16KB [s32-block][d][s-quarter]

    const int tid = threadIdx.x;
    const int wave = tid >> 6, lane = tid & 63;
    const int g = lane >> 4, lr = lane & 15;
    const int q = lane >> 2;
    const int cswz = ((lane & 3) ^ ((lane >> 3) & 3)) << 3;
    const int pcs  = (g ^ ((lr >> 1) & 3)) << 3;
    const int pair = wave >> 1;       // t-half (32 t)
    const int shalf = wave & 1;       // s-half (64 s per 128-chunk)

    const int bid = blockIdx.x;
    const int bh = ((bid & 7) << 2) | (bid >> 8);   // XCD-affinity
    const int qBase = ((bid >> 3) & 31) << 6;

    const bf16* Qg = Q + ((size_t)bh * 2048 + qBase) * 64;
    const bf16* Kg = Kt + (size_t)bh * 2048 * 64;
    const bf16* Vg = Vt + (size_t)bh * 64 * 2048;

    // stage Q: 8 batches of 1KB, 2 per wave, plane-split, swizzled source
#pragma unroll
    for (int i = 0; i < 2; i++) {
        int bi = (wave << 1) + i;
        int p = bi >> 2, rb = (bi & 3) << 4;
        gld_lds16(Qg + (rb + q) * 64 + (p << 5) + cswz, &Qs[p][rb][0]);
    }
    __syncthreads();

    bf16x8 qf[2][2];   // [ks][tt] — this wave's 2 t-tiles
#pragma unroll
    for (int ks = 0; ks < 2; ks++)
#pragma unroll
        for (int tt = 0; tt < 2; tt++)
            qf[ks][tt] = *(const bf16x8*)&Qs[ks][(pair << 5) + (tt << 4) + lr][pcs];

    bf16x8 ones;
#pragma unroll
    for (int i = 0; i < 8; i++) ones[i] = (bf16)1.0f;

    f32x4 oacc[2][4] = {};   // [tt][jd]
    f32x4 oaccL[2] = {};

    for (int s0 = 0; s0 < 2048; s0 += 128) {
        __syncthreads();   // all waves' Ks/Vs (and initial qf) reads drained before re-stage
#pragma unroll
        for (int i = 0; i < 4; i++) {
            int bi = (wave << 2) + i;
            {   // K chunk: [2][128][32]
                int p = bi >> 3, rb = (bi & 7) << 4;
                gld_lds16(Kg + (size_t)(s0 + rb + q) * 64 + (p << 5) + cswz, &Ks[p][rb][0]);
            }
            {   // V chunk: [4][64][32]
                int p = bi >> 2, rb = (bi & 3) << 4;
                gld_lds16(Vg + (size_t)(rb + q) * 2048 + s0 + (p << 5) + cswz, &Vs[p][rb][0]);
            }
        }
        __syncthreads();

#pragma unroll
        for (int sblk = 0; sblk < 2; sblk++) {
            // S^T for this wave's 32-s sub-slice x its 32 t
            f32x4 sacc[2][2] = {};   // [isub][tt]
            __builtin_amdgcn_s_setprio(1);
#pragma unroll
            for (int ks = 0; ks < 2; ks++)
#pragma unroll
                for (int isub = 0; isub < 2; isub++) {
                    bf16x8 kf = *(const bf16x8*)
                        &Ks[ks][(shalf << 6) + (sblk << 5) + (isub << 4) + lr][pcs];
                    sacc[isub][0] = MFMA16(kf, qf[ks][0], sacc[isub][0]);
                    sacc[isub][1] = MFMA16(kf, qf[ks][1], sacc[isub][1]);
                }
            __builtin_amdgcn_s_setprio(0);
            // exp2 + in-register redistribution into PV A-fragments (no LDS)
            bf16x8 pf[2];
#pragma unroll
            for (int tt = 0; tt < 2; tt++) {
                bf16x4 e0, e1;
#pragma unroll
                for (int r = 0; r < 4; r++) {
                    e0[r] = (bf16)__builtin_amdgcn_exp2f(sacc[0][tt][r]);   // s = 4g+r
                    e1[r] = (bf16)__builtin_amdgcn_exp2f(sacc[1][tt][r]);   // s = 16+4g+r
                }
                u32x2 a = __builtin_bit_cast(u32x2, e0);
                u32x2 b = __builtin_bit_cast(u32x2, e1);
                u32x2 t0  = __builtin_amdgcn_permlane32_swap(a.x, b.x, false, false);
                u32x2 w02 = __builtin_amdgcn_permlane16_swap(t0.x, t0.y, false, false);
                u32x2 t1  = __builtin_amdgcn_permlane32_swap(a.y, b.y, false, false);
                u32x2 w13 = __builtin_amdgcn_permlane16_swap(t1.x, t1.y, false, false);
                u32x4 w = {w02.x, w13.x, w02.y, w13.y};
                pf[tt] = __builtin_bit_cast(bf16x8, w);   // P[t=lr][s=8g+j]
            }
            // O += P @ V; L += P @ ones
            __builtin_amdgcn_s_setprio(1);
#pragma unroll
            for (int jd = 0; jd < 4; jd++) {
                bf16x8 vf = *(const bf16x8*)&Vs[(shalf << 1) + sblk][(jd << 4) + lr][pcs];
                oacc[0][jd] = MFMA16(pf[0], vf, oacc[0][jd]);
                oacc[1][jd] = MFMA16(pf[1], vf, oacc[1][jd]);
            }
            oaccL[0] = MFMA16(pf[0], ones, oaccL[0]);
            oaccL[1] = MFMA16(pf[1], ones, oaccL[1]);
            __builtin_amdgcn_s_setprio(0);
        }
    }

    // ---- endgame: 2-way cross-wave reduce (s-half partners share a t-pair) ----
    __syncthreads();   // all waves done with Ks/Vs
    float* Odump = (float*)&Ks[0][0][0];   // 16KB = 2 pairs x 2048 floats
    float* Ldump = (float*)&Vs[0][0][0];   // 4KB used
    if (shalf == 1) {
#pragma unroll
        for (int tt = 0; tt < 2; tt++) {
#pragma unroll
            for (int jd = 0; jd < 4; jd++)
                *(f32x4*)&Odump[(pair << 11) + (((tt << 2) + jd) << 8) + (lane << 2)] = oacc[tt][jd];
            *(f32x4*)&Ldump[(pair << 9) + (tt << 8) + (lane << 2)] = oaccL[tt];
        }
    }
    __syncthreads();
    if (shalf == 0) {
        const int b = bh >> 4, h = bh & 15;
#pragma unroll
        for (int tt = 0; tt < 2; tt++) {
            f32x4 Lp = *(const f32x4*)&Ldump[(pair << 9) + (tt << 8) + (lane << 2)];
            f32x4 Ls = oaccL[tt] + Lp;
            float linv[4];
#pragma unroll
            for (int r = 0; r < 4; r++) linv[r] = 1.0f / Ls[r];
#pragma unroll
            for (int jd = 0; jd < 4; jd++) {
                f32x4 Op = *(const f32x4*)&Odump[(pair << 11) + (((tt << 2) + jd) << 8) + (lane << 2)];
                f32x4 v = oacc[tt][jd] + Op;
#pragma unroll
                for (int r = 0; r < 4; r++) {
                    int t = qBase + (pair << 5) + (tt << 4) + (g << 2) + r;
                    int col = (h << 6) + (jd << 4) + lr;
                    O[(((size_t)(b * 2048 + t)) << 10) + col] = (bf16)(v[r] * linv[r]);
                }
            }
        }
    }
}

extern "C" void kernel_launch(void* const* d_in, const int* in_sizes, int n_in,
                              void* d_out, int out_size, void* d_ws, size_t ws_size,
                              hipStream_t stream) {
    const float* x  = (const float*)d_in[0];
    const float* Wq = (const float*)d_in[1];
    const float* Wk = (const float*)d_in[2];
    const float* Wv = (const float*)d_in[3];
    const float* Wu = (const float*)d_in[4];
    const float* bu = (const float*)d_in[5];
    float* out = (float*)d_out;

    char* ws = (char*)d_ws;
    bf16* xbf  = (bf16*)(ws);                      // 8MB; reused as attn output after QKV GEMM
    bf16* wqbf = (bf16*)(ws + ((size_t)8  << 20)); // wq+wk contiguous = stacked [2048][1024]
    bf16* wkbf = (bf16*)(ws + ((size_t)10 << 20));
    bf16* wvbf = (bf16*)(ws + ((size_t)12 << 20));
    bf16* wubf = (bf16*)(ws + ((size_t)14 << 20));
    bf16* Qb   = (bf16*)(ws + ((size_t)16 << 20)); // [b,h,t,d] 8MB
    bf16* Kb   = (bf16*)(ws + ((size_t)24 << 20)); // [b,h,t,d] 8MB
    bf16* Vtb  = (bf16*)(ws + ((size_t)32 << 20)); // [b,h,d,t] 8MB
    bf16* attnO = xbf;                             // overlay: x dead after gemm_qkv

    const float iscale_k = 0.17677669529663687f;   // 1024^-0.25
    const float iscale_q = 0.25503540109f;         // 1024^-0.25 * log2(e) -> scores in log2 domain

    cvt_all<<<8192, 256, 0, stream>>>(x, Wq, Wk, Wv, Wu, xbf, wqbf, wkbf, wvbf, wubf,
                                      iscale_q, iscale_k);

    gemm_qkv<<<dim3(32, 24), 256, 0, stream>>>(xbf, wqbf, wvbf, Qb, Kb, Vtb);
    attn<<<dim3(1024), 256, 0, stream>>>(Qb, Kb, Vtb, attnO);
    gemm_out<<<dim3(32, 8), 256, 0, stream>>>(wubf, attnO, bu, out);
}